// Round 1
// baseline (644.937 us; speedup 1.0000x reference)
//
#include <hip/hip_runtime.h>
#include <cstdint>
#include <cstddef>

typedef __bf16 bf16_t;
typedef __bf16 bf16x8 __attribute__((ext_vector_type(8)));
typedef __bf16 bf16x4 __attribute__((ext_vector_type(4)));
typedef float f32x4 __attribute__((ext_vector_type(4)));

#define T_LEN 2048
#define DMODEL 4096
#define NHEADS 32
#define KVHEADS 8
#define HD 128
#define QD 4096   // NHEADS*HD
#define KD 1024   // KVHEADS*HD
#define QKVD 6144 // QD + 2*KD
#define WIN 1024

// ---------------- positions (argmax of segment row, first occurrence) ----------------
__global__ void pos_kernel(const int* __restrict__ seg, int* __restrict__ positions) {
  __shared__ int svals[256], sidx[256];
  int tid = threadIdx.x;
  int bestv = -2147483647 - 1, besti = 0;
  for (int t = tid; t < T_LEN; t += 256) {
    int v = seg[t];
    if (v > bestv) { bestv = v; besti = t; }
  }
  svals[tid] = bestv; sidx[tid] = besti;
  __syncthreads();
  for (int st = 128; st > 0; st >>= 1) {
    if (tid < st) {
      if (svals[tid+st] > svals[tid] || (svals[tid+st] == svals[tid] && sidx[tid+st] < sidx[tid])) {
        svals[tid] = svals[tid+st]; sidx[tid] = sidx[tid+st];
      }
    }
    __syncthreads();
  }
  int amax = sidx[0];
  for (int t = tid; t < T_LEN; t += 256)
    positions[t] = (seg[t] != 0) ? (t - amax) : (1 << 30);
}

// ---------------- rope sin/cos table: sc[t][i][2], i in [0,64) ----------------
__global__ void sincos_kernel(const int* __restrict__ positions, float* __restrict__ sc) {
  int t = blockIdx.x, i = threadIdx.x; // 64 threads
  float inv = expf(-(float)i * (logf(500000.0f) / 64.0f));
  float ang = (float)positions[t] * inv;
  sc[(t*64 + i)*2 + 0] = sinf(ang);
  sc[(t*64 + i)*2 + 1] = cosf(ang);
}

// ---------------- f32 -> bf16 convert (8/thread) ----------------
__global__ void cvt_kernel(const float* __restrict__ in, bf16_t* __restrict__ out, int n) {
  int i = (blockIdx.x * blockDim.x + threadIdx.x) * 8;
  if (i >= n) return;
  float4 a = *(const float4*)(in + i);
  float4 b = *(const float4*)(in + i + 4);
  bf16x8 o;
  o[0]=(bf16_t)a.x; o[1]=(bf16_t)a.y; o[2]=(bf16_t)a.z; o[3]=(bf16_t)a.w;
  o[4]=(bf16_t)b.x; o[5]=(bf16_t)b.y; o[6]=(bf16_t)b.z; o[7]=(bf16_t)b.w;
  *(bf16x8*)(out + i) = o;
}

// ---------------- transpose + convert: W[K][N] f32 -> Wt[N][K] bf16 ----------------
__global__ void transcvt_kernel(const float* __restrict__ W, bf16_t* __restrict__ Wt, int K, int N) {
  __shared__ float tile[32][33];
  int tx = threadIdx.x, ty = threadIdx.y; // 32 x 8
  int bx = blockIdx.x, by = blockIdx.y;
  #pragma unroll
  for (int i = 0; i < 4; i++) {
    int k = by*32 + ty + i*8;
    tile[ty + i*8][tx] = W[(size_t)k * N + bx*32 + tx];
  }
  __syncthreads();
  #pragma unroll
  for (int i = 0; i < 4; i++) {
    int n = bx*32 + ty + i*8;
    Wt[(size_t)n * K + by*32 + tx] = (bf16_t)tile[tx][ty + i*8];
  }
}

// ---------------- bf16 GEMM: C[M][N] = A[M][K] * B^T[N][K]^T (m97-style) ----------------
__device__ __forceinline__ void gld_lds16(const void* g, void* l) {
  __builtin_amdgcn_global_load_lds((__attribute__((address_space(1))) void*)g,
                                   (__attribute__((address_space(3))) void*)l, 16, 0, 0);
}

__global__ __launch_bounds__(256) void gemm_kernel(const bf16_t* __restrict__ A,
                                                   const bf16_t* __restrict__ Bt,
                                                   bf16_t* __restrict__ Cb,
                                                   float* __restrict__ Cf,
                                                   int M, int N, int K) {
  __shared__ bf16_t As[128*64];
  __shared__ bf16_t Bs[128*64];
  int tid = threadIdx.x;
  int w = tid >> 6, l = tid & 63;
  int wr = w >> 1, wc = w & 1;
  int lr = l & 15, lg = l >> 4;
  int bm = blockIdx.x, bn = blockIdx.y;
  f32x4 acc[4][4] = {};
  const size_t Abase = (size_t)bm * 128 * K;
  const size_t Bbase = (size_t)bn * 128 * K;
  for (int kt = 0; kt < K; kt += 64) {
    #pragma unroll
    for (int i = 0; i < 4; i++) {
      int eo = (w*4 + i) * 512 + l*8;      // element offset in 128x64 tile
      int row = eo >> 6, col = eo & 63;
      gld_lds16(A + Abase + (size_t)row * K + kt + col, As + (w*4 + i) * 512);
    }
    #pragma unroll
    for (int i = 0; i < 4; i++) {
      int eo = (w*4 + i) * 512 + l*8;
      int row = eo >> 6, col = eo & 63;
      gld_lds16(Bt + Bbase + (size_t)row * K + kt + col, Bs + (w*4 + i) * 512);
    }
    __syncthreads();
    #pragma unroll
    for (int kk = 0; kk < 2; kk++) {
      bf16x8 a[4], b[4];
      #pragma unroll
      for (int mi = 0; mi < 4; mi++)
        a[mi] = *(const bf16x8*)(As + (wr*64 + mi*16 + lr)*64 + kk*32 + lg*8);
      #pragma unroll
      for (int ni = 0; ni < 4; ni++)
        b[ni] = *(const bf16x8*)(Bs + (wc*64 + ni*16 + lr)*64 + kk*32 + lg*8);
      #pragma unroll
      for (int mi = 0; mi < 4; mi++)
        #pragma unroll
        for (int ni = 0; ni < 4; ni++)
          acc[mi][ni] = __builtin_amdgcn_mfma_f32_16x16x32_bf16(a[mi], b[ni], acc[mi][ni], 0, 0, 0);
    }
    __syncthreads();
  }
  #pragma unroll
  for (int mi = 0; mi < 4; mi++) {
    #pragma unroll
    for (int ni = 0; ni < 4; ni++) {
      #pragma unroll
      for (int r = 0; r < 4; r++) {
        int row = bm*128 + wr*64 + mi*16 + lg*4 + r;
        int col = bn*128 + wc*64 + ni*16 + lr;
        if (Cb) Cb[(size_t)row * N + col] = (bf16_t)acc[mi][ni][r];
        else    Cf[(size_t)row * N + col] = acc[mi][ni][r];
      }
    }
  }
}

// ---------------- fused RMSNorm (q over 4096, k over 1024) + RoPE + q-scale ----------------
__global__ __launch_bounds__(256) void normrope_kernel(bf16_t* __restrict__ qkv,
    const float* __restrict__ qw, const float* __restrict__ kw,
    const float* __restrict__ sc) {
  int t = blockIdx.x;
  int tid = threadIdx.x;
  bf16_t* qrow = qkv + (size_t)t * QKVD;
  bf16_t* krow = qrow + QD;
  __shared__ float red[8];
  float s = 0.f;
  {
    const bf16x8* p = (const bf16x8*)(qrow + tid*16);
    bf16x8 v0 = p[0], v1 = p[1];
    #pragma unroll
    for (int j = 0; j < 8; j++) { float a = (float)v0[j], b = (float)v1[j]; s += a*a + b*b; }
  }
  #pragma unroll
  for (int o = 32; o; o >>= 1) s += __shfl_xor(s, o);
  if ((tid & 63) == 0) red[tid >> 6] = s;
  float sk = 0.f;
  {
    bf16x4 v = *(const bf16x4*)(krow + tid*4);
    #pragma unroll
    for (int j = 0; j < 4; j++) { float a = (float)v[j]; sk += a*a; }
  }
  #pragma unroll
  for (int o = 32; o; o >>= 1) sk += __shfl_xor(sk, o);
  if ((tid & 63) == 0) red[4 + (tid >> 6)] = sk;
  __syncthreads();
  float rq = rsqrtf((red[0]+red[1]+red[2]+red[3]) / (float)QD + 1e-6f);
  float rk = rsqrtf((red[4]+red[5]+red[6]+red[7]) / (float)KD + 1e-6f);
  const float ascale = 0.08838834764831845f; // 1/sqrt(128), folded into Q
  for (int p = tid; p < 2048; p += 256) {   // 32 heads * 64 pairs
    int hh = p >> 6, i = p & 63;
    int i1 = hh*HD + i, i2 = i1 + 64;
    float x1 = (float)qrow[i1] * rq * qw[i1];
    float x2 = (float)qrow[i2] * rq * qw[i2];
    float sn = sc[(t*64 + i)*2 + 0], cs = sc[(t*64 + i)*2 + 1];
    qrow[i1] = (bf16_t)((x1*cs - x2*sn) * ascale);
    qrow[i2] = (bf16_t)((x2*cs + x1*sn) * ascale);
  }
  for (int p = tid; p < 512; p += 256) {    // 8 kv heads * 64 pairs
    int hh = p >> 6, i = p & 63;
    int i1 = hh*HD + i, i2 = i1 + 64;
    float x1 = (float)krow[i1] * rk * kw[i1];
    float x2 = (float)krow[i2] * rk * kw[i2];
    float sn = sc[(t*64 + i)*2 + 0], cs = sc[(t*64 + i)*2 + 1];
    krow[i1] = (bf16_t)(x1*cs - x2*sn);
    krow[i2] = (bf16_t)(x2*cs + x1*sn);
  }
}

// ---------------- flash attention, sliding window, GQA ----------------
// grid: (T/64, NHEADS); 4 waves, each owns 16 q rows. KV tile = 32 keys.
__global__ __launch_bounds__(256) void attn_kernel(const bf16_t* __restrict__ qkv,
    const int* __restrict__ positions, const int* __restrict__ seg,
    bf16_t* __restrict__ O) {
  __shared__ bf16_t Vt[HD * 32];      // V tile transposed: [128 d][32 keys]
  __shared__ bf16_t P[4][16 * 32];    // per-wave P tile [16 q][32 keys]
  int tid = threadIdx.x;
  int w = tid >> 6, l = tid & 63, lr = l & 15, lg = l >> 4;
  int qb = blockIdx.x * 64;
  int h = blockIdx.y;
  int kvh = h >> 2;
  int q0 = qb + w * 16;
  bf16x8 qf[4];
  {
    const bf16_t* Qrow = qkv + (size_t)(q0 + lr) * QKVD + h * HD;
    #pragma unroll
    for (int c = 0; c < 4; c++) qf[c] = *(const bf16x8*)(Qrow + c*32 + lg*8);
  }
  int pos_i[4], seg_i[4];
  #pragma unroll
  for (int r = 0; r < 4; r++) { int i = q0 + lg*4 + r; pos_i[r] = positions[i]; seg_i[r] = seg[i]; }
  f32x4 o[8] = {};
  float m[4], lsum[4];
  #pragma unroll
  for (int r = 0; r < 4; r++) { m[r] = -__builtin_inff(); lsum[r] = 0.f; }
  int jstart = qb - (WIN - 1); if (jstart < 0) jstart = 0; jstart &= ~31;
  const int jlast = qb + 32;
  for (int j0 = jstart; j0 <= jlast; j0 += 32) {
    // stage V tile transposed (all 256 threads)
    #pragma unroll
    for (int si = 0; si < 2; si++) {
      int sgm = tid + si * 256;
      int key = sgm >> 4, dp = sgm & 15;
      bf16x8 vv = *(const bf16x8*)(qkv + (size_t)(j0 + key) * QKVD + QD + KD + kvh*HD + dp*8);
      #pragma unroll
      for (int e = 0; e < 8; e++) Vt[(dp*8 + e)*32 + key] = vv[e];
    }
    __syncthreads();
    bool active = (j0 <= q0 + 15) && (j0 + 31 >= q0 - (WIN - 1));
    if (active) {
      f32x4 s[2] = {};
      #pragma unroll
      for (int kt = 0; kt < 2; kt++) {
        const bf16_t* Krow = qkv + (size_t)(j0 + kt*16 + lr) * QKVD + QD + kvh*HD;
        #pragma unroll
        for (int c = 0; c < 4; c++) {
          bf16x8 kf = *(const bf16x8*)(Krow + c*32 + lg*8);
          s[kt] = __builtin_amdgcn_mfma_f32_16x16x32_bf16(qf[c], kf, s[kt], 0, 0, 0);
        }
      }
      #pragma unroll
      for (int kt = 0; kt < 2; kt++) {
        int j = j0 + kt*16 + lr;
        int pj = positions[j]; int sj = seg[j];
        #pragma unroll
        for (int r = 0; r < 4; r++) {
          bool valid = (pj <= pos_i[r]) && (pos_i[r] - pj < WIN) && (seg_i[r] == sj) && (sj != 0);
          s[kt][r] = valid ? s[kt][r] : -__builtin_inff();
        }
      }
      #pragma unroll
      for (int r = 0; r < 4; r++) {
        float rm = fmaxf(s[0][r], s[1][r]);
        #pragma unroll
        for (int o2 = 1; o2 < 16; o2 <<= 1) rm = fmaxf(rm, __shfl_xor(rm, o2));
        float mn = fmaxf(m[r], rm);
        float mu = fmaxf(mn, -1e38f);
        float p0 = __expf(s[0][r] - mu);
        float p1 = __expf(s[1][r] - mu);
        float rescale = __expf(m[r] - mu);
        m[r] = mn;
        float rs = p0 + p1;
        #pragma unroll
        for (int o2 = 1; o2 < 16; o2 <<= 1) rs += __shfl_xor(rs, o2);
        lsum[r] = lsum[r] * rescale + rs;
        #pragma unroll
        for (int n = 0; n < 8; n++) o[n][r] *= rescale;
        P[w][(lg*4 + r)*32 + lr]      = (bf16_t)p0;
        P[w][(lg*4 + r)*32 + 16 + lr] = (bf16_t)p1;
      }
    }
    __syncthreads();
    if (active) {
      bf16x8 pa = *(const bf16x8*)(&P[w][lr*32 + lg*8]);
      #pragma unroll
      for (int n = 0; n < 8; n++) {
        bf16x8 vb = *(const bf16x8*)(&Vt[(n*16 + lr)*32 + lg*8]);
        o[n] = __builtin_amdgcn_mfma_f32_16x16x32_bf16(pa, vb, o[n], 0, 0, 0);
      }
    }
    __syncthreads();
  }
  #pragma unroll
  for (int r = 0; r < 4; r++) {
    float inv = lsum[r] > 0.f ? 1.f / lsum[r] : 0.f;
    int row = q0 + lg*4 + r;
    #pragma unroll
    for (int n = 0; n < 8; n++)
      O[(size_t)row * QD + h*HD + n*16 + lr] = (bf16_t)(o[n][r] * inv);
  }
}

// ---------------- launch ----------------
extern "C" void kernel_launch(void* const* d_in, const int* in_sizes, int n_in,
                              void* d_out, int out_size, void* d_ws, size_t ws_size,
                              hipStream_t stream) {
  (void)in_sizes; (void)n_in; (void)out_size; (void)ws_size;
  const float* x  = (const float*)d_in[0];
  const float* Wq = (const float*)d_in[1];
  const float* Wk = (const float*)d_in[2];
  const float* Wv = (const float*)d_in[3];
  const float* Wo = (const float*)d_in[4];
  const float* qw = (const float*)d_in[5];
  const float* kw = (const float*)d_in[6];
  const int*  seg = (const int*)d_in[7];
  float* out = (float*)d_out;

  char* base = (char*)d_ws;
  size_t off = 0;
  auto alloc = [&](size_t b) { void* r = base + off; off = (off + b + 255) & ~(size_t)255; return r; };
  bf16_t* xb    = (bf16_t*)alloc((size_t)T_LEN * DMODEL * 2);   // also reused as attention output
  bf16_t* Wallt = (bf16_t*)alloc((size_t)QKVD * DMODEL * 2);    // [6144][4096] = [Wq^T; Wk^T; Wv^T]
  bf16_t* Wot   = (bf16_t*)alloc((size_t)DMODEL * QD * 2);      // Wo^T [4096][4096]
  bf16_t* qkv   = (bf16_t*)alloc((size_t)T_LEN * QKVD * 2);     // [2048][6144]
  int*    posi  = (int*)alloc((size_t)T_LEN * 4);
  float*  sc    = (float*)alloc((size_t)T_LEN * 64 * 2 * 4);
  bf16_t* ao    = xb;  // attention output aliases xb (xb dead after GEMM1)

  pos_kernel<<<1, 256, 0, stream>>>(seg, posi);
  sincos_kernel<<<T_LEN, 64, 0, stream>>>(posi, sc);
  cvt_kernel<<<(T_LEN * DMODEL / 8 + 255) / 256, 256, 0, stream>>>(x, xb, T_LEN * DMODEL);
  transcvt_kernel<<<dim3(QD/32, DMODEL/32), dim3(32, 8), 0, stream>>>(Wq, Wallt, DMODEL, QD);
  transcvt_kernel<<<dim3(KD/32, DMODEL/32), dim3(32, 8), 0, stream>>>(Wk, Wallt + (size_t)QD * DMODEL, DMODEL, KD);
  transcvt_kernel<<<dim3(KD/32, DMODEL/32), dim3(32, 8), 0, stream>>>(Wv, Wallt + (size_t)(QD + KD) * DMODEL, DMODEL, KD);
  transcvt_kernel<<<dim3(DMODEL/32, QD/32), dim3(32, 8), 0, stream>>>(Wo, Wot, QD, DMODEL);
  gemm_kernel<<<dim3(T_LEN/128, QKVD/128), 256, 0, stream>>>(xb, Wallt, qkv, nullptr, T_LEN, QKVD, DMODEL);
  normrope_kernel<<<T_LEN, 256, 0, stream>>>(qkv, qw, kw, sc);
  attn_kernel<<<dim3(T_LEN/64, NHEADS), 256, 0, stream>>>(qkv, posi, seg, ao);
  gemm_kernel<<<dim3(T_LEN/128, DMODEL/128), 256, 0, stream>>>(ao, Wot, nullptr, out, T_LEN, DMODEL, QD);
}

// Round 2
// 541.204 us; speedup vs baseline: 1.1917x; 1.1917x over previous
//
#include <hip/hip_runtime.h>
#include <cstdint>
#include <cstddef>

typedef __bf16 bf16_t;
typedef __bf16 bf16x8 __attribute__((ext_vector_type(8)));
typedef __bf16 bf16x4 __attribute__((ext_vector_type(4)));
typedef __bf16 bf16x2 __attribute__((ext_vector_type(2)));
typedef float f32x4 __attribute__((ext_vector_type(4)));

#define T_LEN 2048
#define DMODEL 4096
#define NHEADS 32
#define KVHEADS 8
#define HD 128
#define QD 4096   // NHEADS*HD
#define KD 1024   // KVHEADS*HD
#define QKVD 6144 // QD + 2*KD
#define WIN 1024
#define VS 72     // padded stride for Vt/P tiles (144B = 9*16B rows)

// ---------------- positions (argmax of segment row, first occurrence) ----------------
__global__ void pos_kernel(const int* __restrict__ seg, int* __restrict__ positions) {
  __shared__ int svals[256], sidx[256];
  int tid = threadIdx.x;
  int bestv = -2147483647 - 1, besti = 0;
  for (int t = tid; t < T_LEN; t += 256) {
    int v = seg[t];
    if (v > bestv) { bestv = v; besti = t; }
  }
  svals[tid] = bestv; sidx[tid] = besti;
  __syncthreads();
  for (int st = 128; st > 0; st >>= 1) {
    if (tid < st) {
      if (svals[tid+st] > svals[tid] || (svals[tid+st] == svals[tid] && sidx[tid+st] < sidx[tid])) {
        svals[tid] = svals[tid+st]; sidx[tid] = sidx[tid+st];
      }
    }
    __syncthreads();
  }
  int amax = sidx[0];
  for (int t = tid; t < T_LEN; t += 256)
    positions[t] = (seg[t] != 0) ? (t - amax) : (1 << 30);
}

// ---------------- rope sin/cos table: sc[t][i][2], i in [0,64) ----------------
__global__ void sincos_kernel(const int* __restrict__ positions, float* __restrict__ sc) {
  int t = blockIdx.x, i = threadIdx.x; // 64 threads
  float inv = expf(-(float)i * (logf(500000.0f) / 64.0f));
  float ang = (float)positions[t] * inv;
  sc[(t*64 + i)*2 + 0] = sinf(ang);
  sc[(t*64 + i)*2 + 1] = cosf(ang);
}

// ---------------- f32 -> bf16 convert (8/thread) ----------------
__global__ void cvt_kernel(const float* __restrict__ in, bf16_t* __restrict__ out, int n) {
  int i = (blockIdx.x * blockDim.x + threadIdx.x) * 8;
  if (i >= n) return;
  float4 a = *(const float4*)(in + i);
  float4 b = *(const float4*)(in + i + 4);
  bf16x8 o;
  o[0]=(bf16_t)a.x; o[1]=(bf16_t)a.y; o[2]=(bf16_t)a.z; o[3]=(bf16_t)a.w;
  o[4]=(bf16_t)b.x; o[5]=(bf16_t)b.y; o[6]=(bf16_t)b.z; o[7]=(bf16_t)b.w;
  *(bf16x8*)(out + i) = o;
}

// ---------------- transpose + convert: W[K][N] f32 -> Wt[N][K] bf16 ----------------
__global__ void transcvt_kernel(const float* __restrict__ W, bf16_t* __restrict__ Wt, int K, int N) {
  __shared__ float tile[32][33];
  int tx = threadIdx.x, ty = threadIdx.y; // 32 x 8
  int bx = blockIdx.x, by = blockIdx.y;
  #pragma unroll
  for (int i = 0; i < 4; i++) {
    int k = by*32 + ty + i*8;
    tile[ty + i*8][tx] = W[(size_t)k * N + bx*32 + tx];
  }
  __syncthreads();
  #pragma unroll
  for (int i = 0; i < 4; i++) {
    int n = bx*32 + ty + i*8;
    Wt[(size_t)n * K + by*32 + tx] = (bf16_t)tile[tx][ty + i*8];
  }
}

// ---------------- bf16 GEMM: C[M][N] = A[M][K] * B^T[N][K]^T (m97-style) ----------------
__device__ __forceinline__ void gld_lds16(const void* g, void* l) {
  __builtin_amdgcn_global_load_lds((__attribute__((address_space(1))) void*)g,
                                   (__attribute__((address_space(3))) void*)l, 16, 0, 0);
}

__global__ __launch_bounds__(256) void gemm_kernel(const bf16_t* __restrict__ A,
                                                   const bf16_t* __restrict__ Bt,
                                                   bf16_t* __restrict__ Cb,
                                                   float* __restrict__ Cf,
                                                   int M, int N, int K) {
  __shared__ bf16_t As[128*64];
  __shared__ bf16_t Bs[128*64];
  int tid = threadIdx.x;
  int w = tid >> 6, l = tid & 63;
  int wr = w >> 1, wc = w & 1;
  int lr = l & 15, lg = l >> 4;
  int bm = blockIdx.x, bn = blockIdx.y;
  f32x4 acc[4][4] = {};
  const size_t Abase = (size_t)bm * 128 * K;
  const size_t Bbase = (size_t)bn * 128 * K;
  for (int kt = 0; kt < K; kt += 64) {
    #pragma unroll
    for (int i = 0; i < 4; i++) {
      int eo = (w*4 + i) * 512 + l*8;      // element offset in 128x64 tile
      int row = eo >> 6, col = eo & 63;
      gld_lds16(A + Abase + (size_t)row * K + kt + col, As + (w*4 + i) * 512);
    }
    #pragma unroll
    for (int i = 0; i < 4; i++) {
      int eo = (w*4 + i) * 512 + l*8;
      int row = eo >> 6, col = eo & 63;
      gld_lds16(Bt + Bbase + (size_t)row * K + kt + col, Bs + (w*4 + i) * 512);
    }
    __syncthreads();
    #pragma unroll
    for (int kk = 0; kk < 2; kk++) {
      bf16x8 a[4], b[4];
      #pragma unroll
      for (int mi = 0; mi < 4; mi++)
        a[mi] = *(const bf16x8*)(As + (wr*64 + mi*16 + lr)*64 + kk*32 + lg*8);
      #pragma unroll
      for (int ni = 0; ni < 4; ni++)
        b[ni] = *(const bf16x8*)(Bs + (wc*64 + ni*16 + lr)*64 + kk*32 + lg*8);
      #pragma unroll
      for (int mi = 0; mi < 4; mi++)
        #pragma unroll
        for (int ni = 0; ni < 4; ni++)
          acc[mi][ni] = __builtin_amdgcn_mfma_f32_16x16x32_bf16(a[mi], b[ni], acc[mi][ni], 0, 0, 0);
    }
    __syncthreads();
  }
  #pragma unroll
  for (int mi = 0; mi < 4; mi++) {
    #pragma unroll
    for (int ni = 0; ni < 4; ni++) {
      #pragma unroll
      for (int r = 0; r < 4; r++) {
        int row = bm*128 + wr*64 + mi*16 + lg*4 + r;
        int col = bn*128 + wc*64 + ni*16 + lr;
        if (Cb) Cb[(size_t)row * N + col] = (bf16_t)acc[mi][ni][r];
        else    Cf[(size_t)row * N + col] = acc[mi][ni][r];
      }
    }
  }
}

// ---------------- fused RMSNorm (q over 4096, k over 1024) + RoPE + q-scale ----------------
__global__ __launch_bounds__(256) void normrope_kernel(bf16_t* __restrict__ qkv,
    const float* __restrict__ qw, const float* __restrict__ kw,
    const float* __restrict__ sc) {
  int t = blockIdx.x;
  int tid = threadIdx.x;
  bf16_t* qrow = qkv + (size_t)t * QKVD;
  bf16_t* krow = qrow + QD;
  __shared__ float red[8];
  float s = 0.f;
  {
    const bf16x8* p = (const bf16x8*)(qrow + tid*16);
    bf16x8 v0 = p[0], v1 = p[1];
    #pragma unroll
    for (int j = 0; j < 8; j++) { float a = (float)v0[j], b = (float)v1[j]; s += a*a + b*b; }
  }
  #pragma unroll
  for (int o = 32; o; o >>= 1) s += __shfl_xor(s, o);
  if ((tid & 63) == 0) red[tid >> 6] = s;
  float sk = 0.f;
  {
    bf16x4 v = *(const bf16x4*)(krow + tid*4);
    #pragma unroll
    for (int j = 0; j < 4; j++) { float a = (float)v[j]; sk += a*a; }
  }
  #pragma unroll
  for (int o = 32; o; o >>= 1) sk += __shfl_xor(sk, o);
  if ((tid & 63) == 0) red[4 + (tid >> 6)] = sk;
  __syncthreads();
  float rq = rsqrtf((red[0]+red[1]+red[2]+red[3]) / (float)QD + 1e-6f);
  float rk = rsqrtf((red[4]+red[5]+red[6]+red[7]) / (float)KD + 1e-6f);
  const float ascale = 0.08838834764831845f; // 1/sqrt(128), folded into Q
  for (int p = tid; p < 2048; p += 256) {   // 32 heads * 64 pairs
    int hh = p >> 6, i = p & 63;
    int i1 = hh*HD + i, i2 = i1 + 64;
    float x1 = (float)qrow[i1] * rq * qw[i1];
    float x2 = (float)qrow[i2] * rq * qw[i2];
    float sn = sc[(t*64 + i)*2 + 0], cs = sc[(t*64 + i)*2 + 1];
    qrow[i1] = (bf16_t)((x1*cs - x2*sn) * ascale);
    qrow[i2] = (bf16_t)((x2*cs + x1*sn) * ascale);
  }
  for (int p = tid; p < 512; p += 256) {    // 8 kv heads * 64 pairs
    int hh = p >> 6, i = p & 63;
    int i1 = hh*HD + i, i2 = i1 + 64;
    float x1 = (float)krow[i1] * rk * kw[i1];
    float x2 = (float)krow[i2] * rk * kw[i2];
    float sn = sc[(t*64 + i)*2 + 0], cs = sc[(t*64 + i)*2 + 1];
    krow[i1] = (bf16_t)(x1*cs - x2*sn);
    krow[i2] = (bf16_t)(x2*cs + x1*sn);
  }
}

// ---------------- flash attention, sliding window, GQA ----------------
// grid: (T/64, NHEADS); 4 waves, each owns 16 q rows. KV tile = 64 keys.
// Vt/P use padded stride VS=72 (144B) so b128 reads spread over all 8 bank slots.
__global__ __launch_bounds__(256) void attn_kernel(const bf16_t* __restrict__ qkv,
    const int* __restrict__ positions, const int* __restrict__ seg,
    bf16_t* __restrict__ O) {
  __shared__ bf16_t Vt[HD * VS];      // V tile transposed: [128 d][64 keys + pad]
  __shared__ bf16_t P[4][16 * VS];    // per-wave P tile [16 q][64 keys + pad]
  int tid = threadIdx.x;
  int w = tid >> 6, l = tid & 63, lr = l & 15, lg = l >> 4;
  int qb = blockIdx.x * 64;
  int h = blockIdx.y;
  int kvh = h >> 2;
  int q0 = qb + w * 16;
  bf16x8 qf[4];
  {
    const bf16_t* Qrow = qkv + (size_t)(q0 + lr) * QKVD + h * HD;
    #pragma unroll
    for (int c = 0; c < 4; c++) qf[c] = *(const bf16x8*)(Qrow + c*32 + lg*8);
  }
  int pos_i[4], seg_i[4];
  #pragma unroll
  for (int r = 0; r < 4; r++) { int i = q0 + lg*4 + r; pos_i[r] = positions[i]; seg_i[r] = seg[i]; }
  f32x4 o[8] = {};
  float m[4], lsum[4];
  #pragma unroll
  for (int r = 0; r < 4; r++) { m[r] = -__builtin_inff(); lsum[r] = 0.f; }
  int jstart = qb - (WIN - 1); if (jstart < 0) jstart = 0; jstart &= ~63;
  for (int j0 = jstart; j0 <= qb; j0 += 64) {
    // stage V tile transposed, pair-key b32 writes (bank-even)
    // items: 32 key-pairs x 16 d-groups = 512; thread does 2
    #pragma unroll
    for (int si = 0; si < 2; si++) {
      int item = tid + si * 256;
      int kp = item & 31, dg = item >> 5;
      const bf16_t* v0p = qkv + (size_t)(j0 + 2*kp) * QKVD + QD + KD + kvh*HD + dg*8;
      bf16x8 vA = *(const bf16x8*)(v0p);
      bf16x8 vB = *(const bf16x8*)(v0p + QKVD);
      #pragma unroll
      for (int e = 0; e < 8; e++) {
        bf16x2 pr; pr[0] = vA[e]; pr[1] = vB[e];
        *(bf16x2*)(Vt + (dg*8 + e)*VS + 2*kp) = pr;
      }
    }
    __syncthreads();
    bool active = (j0 <= q0 + 15) && (j0 + 63 >= q0 - (WIN - 1));
    if (active) {
      f32x4 s[4] = {};
      #pragma unroll
      for (int kt = 0; kt < 4; kt++) {
        const bf16_t* Krow = qkv + (size_t)(j0 + kt*16 + lr) * QKVD + QD + kvh*HD;
        #pragma unroll
        for (int c = 0; c < 4; c++) {
          bf16x8 kf = *(const bf16x8*)(Krow + c*32 + lg*8);
          s[kt] = __builtin_amdgcn_mfma_f32_16x16x32_bf16(qf[c], kf, s[kt], 0, 0, 0);
        }
      }
      // mask
      #pragma unroll
      for (int kt = 0; kt < 4; kt++) {
        int j = j0 + kt*16 + lr;
        int pj = positions[j]; int sj = seg[j];
        #pragma unroll
        for (int r = 0; r < 4; r++) {
          bool valid = (pj <= pos_i[r]) && (pos_i[r] - pj < WIN) && (seg_i[r] == sj) && (sj != 0);
          s[kt][r] = valid ? s[kt][r] : -__builtin_inff();
        }
      }
      // online softmax with defer-max (THR=8)
      #pragma unroll
      for (int r = 0; r < 4; r++) {
        float rm = fmaxf(fmaxf(s[0][r], s[1][r]), fmaxf(s[2][r], s[3][r]));
        #pragma unroll
        for (int o2 = 1; o2 < 16; o2 <<= 1) rm = fmaxf(rm, __shfl_xor(rm, o2));
        if (rm > m[r] + 8.f) {
          float rescale = __expf(m[r] - rm);   // m=-inf -> 0
          lsum[r] *= rescale;
          #pragma unroll
          for (int n = 0; n < 8; n++) o[n][r] *= rescale;
          m[r] = rm;
        }
        float mub = fmaxf(m[r], -1e37f);
        float p0 = __expf(s[0][r] - mub);
        float p1 = __expf(s[1][r] - mub);
        float p2 = __expf(s[2][r] - mub);
        float p3 = __expf(s[3][r] - mub);
        float rs = (p0 + p1) + (p2 + p3);
        #pragma unroll
        for (int o2 = 1; o2 < 16; o2 <<= 1) rs += __shfl_xor(rs, o2);
        lsum[r] += rs;
        int prow = (lg*4 + r) * VS;
        P[w][prow + lr]      = (bf16_t)p0;
        P[w][prow + 16 + lr] = (bf16_t)p1;
        P[w][prow + 32 + lr] = (bf16_t)p2;
        P[w][prow + 48 + lr] = (bf16_t)p3;
      }
    }
    __syncthreads();
    if (active) {
      #pragma unroll
      for (int ks = 0; ks < 2; ks++) {
        bf16x8 pa = *(const bf16x8*)(&P[w][lr*VS + ks*32 + lg*8]);
        #pragma unroll
        for (int n = 0; n < 8; n++) {
          bf16x8 vb = *(const bf16x8*)(&Vt[(n*16 + lr)*VS + ks*32 + lg*8]);
          o[n] = __builtin_amdgcn_mfma_f32_16x16x32_bf16(pa, vb, o[n], 0, 0, 0);
        }
      }
    }
    __syncthreads();
  }
  #pragma unroll
  for (int r = 0; r < 4; r++) {
    float inv = lsum[r] > 0.f ? 1.f / lsum[r] : 0.f;
    int row = q0 + lg*4 + r;
    #pragma unroll
    for (int n = 0; n < 8; n++)
      O[(size_t)row * QD + h*HD + n*16 + lr] = (bf16_t)(o[n][r] * inv);
  }
}

// ---------------- launch ----------------
extern "C" void kernel_launch(void* const* d_in, const int* in_sizes, int n_in,
                              void* d_out, int out_size, void* d_ws, size_t ws_size,
                              hipStream_t stream) {
  (void)in_sizes; (void)n_in; (void)out_size; (void)ws_size;
  const float* x  = (const float*)d_in[0];
  const float* Wq = (const float*)d_in[1];
  const float* Wk = (const float*)d_in[2];
  const float* Wv = (const float*)d_in[3];
  const float* Wo = (const float*)d_in[4];
  const float* qw = (const float*)d_in[5];
  const float* kw = (const float*)d_in[6];
  const int*  seg = (const int*)d_in[7];
  float* out = (float*)d_out;

  char* base = (char*)d_ws;
  size_t off = 0;
  auto alloc = [&](size_t b) { void* r = base + off; off = (off + b + 255) & ~(size_t)255; return r; };
  bf16_t* xb    = (bf16_t*)alloc((size_t)T_LEN * DMODEL * 2);   // also reused as attention output
  bf16_t* Wallt = (bf16_t*)alloc((size_t)QKVD * DMODEL * 2);    // [6144][4096] = [Wq^T; Wk^T; Wv^T]
  bf16_t* Wot   = (bf16_t*)alloc((size_t)DMODEL * QD * 2);      // Wo^T [4096][4096]
  bf16_t* qkv   = (bf16_t*)alloc((size_t)T_LEN * QKVD * 2);     // [2048][6144]
  int*    posi  = (int*)alloc((size_t)T_LEN * 4);
  float*  sc    = (float*)alloc((size_t)T_LEN * 64 * 2 * 4);
  bf16_t* ao    = xb;  // attention output aliases xb (xb dead after GEMM1)

  pos_kernel<<<1, 256, 0, stream>>>(seg, posi);
  sincos_kernel<<<T_LEN, 64, 0, stream>>>(posi, sc);
  cvt_kernel<<<(T_LEN * DMODEL / 8 + 255) / 256, 256, 0, stream>>>(x, xb, T_LEN * DMODEL);
  transcvt_kernel<<<dim3(QD/32, DMODEL/32), dim3(32, 8), 0, stream>>>(Wq, Wallt, DMODEL, QD);
  transcvt_kernel<<<dim3(KD/32, DMODEL/32), dim3(32, 8), 0, stream>>>(Wk, Wallt + (size_t)QD * DMODEL, DMODEL, KD);
  transcvt_kernel<<<dim3(KD/32, DMODEL/32), dim3(32, 8), 0, stream>>>(Wv, Wallt + (size_t)(QD + KD) * DMODEL, DMODEL, KD);
  transcvt_kernel<<<dim3(DMODEL/32, QD/32), dim3(32, 8), 0, stream>>>(Wo, Wot, QD, DMODEL);
  gemm_kernel<<<dim3(T_LEN/128, QKVD/128), 256, 0, stream>>>(xb, Wallt, qkv, nullptr, T_LEN, QKVD, DMODEL);
  normrope_kernel<<<T_LEN, 256, 0, stream>>>(qkv, qw, kw, sc);
  attn_kernel<<<dim3(T_LEN/64, NHEADS), 256, 0, stream>>>(qkv, posi, seg, ao);
  gemm_kernel<<<dim3(T_LEN/128, DMODEL/128), 256, 0, stream>>>(ao, Wot, nullptr, out, T_LEN, DMODEL, QD);
}

// Round 3
// 496.516 us; speedup vs baseline: 1.2989x; 1.0900x over previous
//
#include <hip/hip_runtime.h>
#include <cstdint>
#include <cstddef>

typedef __bf16 bf16_t;
typedef __bf16 bf16x8 __attribute__((ext_vector_type(8)));
typedef __bf16 bf16x4 __attribute__((ext_vector_type(4)));
typedef __bf16 bf16x2 __attribute__((ext_vector_type(2)));
typedef float f32x4 __attribute__((ext_vector_type(4)));

#define T_LEN 2048
#define DMODEL 4096
#define NHEADS 32
#define KVHEADS 8
#define HD 128
#define QD 4096   // NHEADS*HD
#define KD 1024   // KVHEADS*HD
#define QKVD 6144 // QD + 2*KD
#define WIN 1024
#define VS 72     // padded stride for attn Vt/P tiles

// ---------------- positions (argmax of segment row, first occurrence) ----------------
__global__ void pos_kernel(const int* __restrict__ seg, int* __restrict__ positions) {
  __shared__ int svals[256], sidx[256];
  int tid = threadIdx.x;
  int bestv = -2147483647 - 1, besti = 0;
  for (int t = tid; t < T_LEN; t += 256) {
    int v = seg[t];
    if (v > bestv) { bestv = v; besti = t; }
  }
  svals[tid] = bestv; sidx[tid] = besti;
  __syncthreads();
  for (int st = 128; st > 0; st >>= 1) {
    if (tid < st) {
      if (svals[tid+st] > svals[tid] || (svals[tid+st] == svals[tid] && sidx[tid+st] < sidx[tid])) {
        svals[tid] = svals[tid+st]; sidx[tid] = sidx[tid+st];
      }
    }
    __syncthreads();
  }
  int amax = sidx[0];
  for (int t = tid; t < T_LEN; t += 256)
    positions[t] = (seg[t] != 0) ? (t - amax) : (1 << 30);
}

// ---------------- rope sin/cos table: sc[t][i][2], i in [0,64) ----------------
__global__ void sincos_kernel(const int* __restrict__ positions, float* __restrict__ sc) {
  int t = blockIdx.x, i = threadIdx.x; // 64 threads
  float inv = expf(-(float)i * (logf(500000.0f) / 64.0f));
  float ang = (float)positions[t] * inv;
  sc[(t*64 + i)*2 + 0] = sinf(ang);
  sc[(t*64 + i)*2 + 1] = cosf(ang);
}

// ---------------- f32 -> bf16 convert (8/thread) ----------------
__global__ void cvt_kernel(const float* __restrict__ in, bf16_t* __restrict__ out, int n) {
  int i = (blockIdx.x * blockDim.x + threadIdx.x) * 8;
  if (i >= n) return;
  float4 a = *(const float4*)(in + i);
  float4 b = *(const float4*)(in + i + 4);
  bf16x8 o;
  o[0]=(bf16_t)a.x; o[1]=(bf16_t)a.y; o[2]=(bf16_t)a.z; o[3]=(bf16_t)a.w;
  o[4]=(bf16_t)b.x; o[5]=(bf16_t)b.y; o[6]=(bf16_t)b.z; o[7]=(bf16_t)b.w;
  *(bf16x8*)(out + i) = o;
}

// ---------------- transpose + convert: W[K][N] f32 -> Wt[N][K] bf16 ----------------
__global__ void transcvt_kernel(const float* __restrict__ W, bf16_t* __restrict__ Wt, int K, int N) {
  __shared__ float tile[32][33];
  int tx = threadIdx.x, ty = threadIdx.y; // 32 x 8
  int bx = blockIdx.x, by = blockIdx.y;
  #pragma unroll
  for (int i = 0; i < 4; i++) {
    int k = by*32 + ty + i*8;
    tile[ty + i*8][tx] = W[(size_t)k * N + bx*32 + tx];
  }
  __syncthreads();
  #pragma unroll
  for (int i = 0; i < 4; i++) {
    int n = bx*32 + ty + i*8;
    Wt[(size_t)n * K + by*32 + tx] = (bf16_t)tile[tx][ty + i*8];
  }
}

// ---------------- 256x256 8-phase bf16 GEMM (T1+T2+T3+T4+T5) ----------------
// C[M][N] = A[M][K] @ Bt[N][K]^T. 512 threads (8 waves, 2M x 4N), BK=64.
// LDS: 2 x (A 256x64 + B 256x64) bf16 = 128 KiB, XOR-swizzled 16B chunks.
__device__ __forceinline__ void gld_lds16(const void* g, void* l) {
  __builtin_amdgcn_global_load_lds((__attribute__((address_space(1))) void*)g,
                                   (__attribute__((address_space(3))) void*)l, 16, 0, 0);
}

#define MFMA_QUAD(FM0, FN0)                                                     \
  { _Pragma("unroll") for (int fm_ = 0; fm_ < 4; fm_++)                          \
    _Pragma("unroll") for (int fn_ = 0; fn_ < 2; fn_++)                          \
    _Pragma("unroll") for (int kk_ = 0; kk_ < 2; kk_++)                          \
      acc[(FM0)+fm_][(FN0)+fn_] = __builtin_amdgcn_mfma_f32_16x16x32_bf16(       \
          a[(FM0)+fm_][kk_], bb[(FN0)+fn_][kk_], acc[(FM0)+fm_][(FN0)+fn_], 0,0,0); }

template<bool WRITE_BF16>
__global__ __launch_bounds__(512, 2) void gemm256_kernel(
    const bf16_t* __restrict__ A, const bf16_t* __restrict__ Bt,
    bf16_t* __restrict__ Cb, float* __restrict__ Cf,
    int M, int N, int K, int NBN) {
  __shared__ bf16_t As[2 * 256 * 64];
  __shared__ bf16_t Bs[2 * 256 * 64];
  int tid = threadIdx.x;
  int w = tid >> 6, l = tid & 63, lr = l & 15, lg = l >> 4;
  int wr = w >> 2, wc = w & 3;         // 2M x 4N wave grid
  // T1: XCD-chunked swizzle (gridDim.x % 8 == 0)
  int nwg = gridDim.x;
  int wg  = blockIdx.x;
  int cpx = nwg >> 3;
  int swz = (wg & 7) * cpx + (wg >> 3);
  int bm = swz / NBN, bn = swz % NBN;
  const int NT = K >> 6;

  // stage one 16KB half-tile of K-tile tt: h=0,1 -> A rows 0..127 / 128..255; h=2,3 -> B
  auto stage = [&](int tt, int h) {
    int b2 = tt & 1;
    const bf16_t* G; size_t grow0; bf16_t* ldsb;
    if (h < 2) { G = A;  grow0 = (size_t)bm*256 + h*128;       ldsb = As + b2*16384 + h*8192; }
    else       { G = Bt; grow0 = (size_t)bn*256 + (h-2)*128;   ldsb = Bs + b2*16384 + (h-2)*8192; }
    int kcol = tt * 64;
    #pragma unroll
    for (int r2 = 0; r2 < 2; r2++) {
      int L = r2*8192 + tid*16;        // byte offset in region (linear LDS dest)
      int row = L >> 7;                // 0..127
      int chunk = (L >> 4) & 7;
      int scn = chunk ^ (row & 7);     // inverse-swizzled global source chunk
      gld_lds16(G + (grow0 + (size_t)row) * K + kcol + scn*8,
                ldsb + r2*4096 + w*512);   // wave-uniform dest; HW adds lane*16B
    }
  };
  auto afrag = [&](int b2, int row, int kk) -> bf16x8 {
    int chunk = (kk*4 + lg) ^ (row & 7);
    return *(const bf16x8*)((const char*)(As + b2*16384) + row*128 + chunk*16);
  };
  auto bfrag = [&](int b2, int row, int kk) -> bf16x8 {
    int chunk = (kk*4 + lg) ^ (row & 7);
    return *(const bf16x8*)((const char*)(Bs + b2*16384) + row*128 + chunk*16);
  };

  f32x4 acc[8][4] = {};
  bf16x8 a[8][2], bb[4][2];

  // prologue: tile0 all 4 halves + tile1 h0..h2  (14 loads/wave-lane)
  #pragma unroll
  for (int h = 0; h < 4; h++) stage(0, h);
  #pragma unroll
  for (int h = 0; h < 3; h++) stage(1, h);
  asm volatile("s_waitcnt vmcnt(6)" ::: "memory");   // tile0 fully landed
  __builtin_amdgcn_s_barrier();

  for (int t = 0; t < NT; t++) {
    int b = t & 1;
    // ---- phase 1: read ALL A (16 b128) + B fn0,1 (4); stage (t+1,h3); MFMA quad m0n0
    #pragma unroll
    for (int fm = 0; fm < 8; fm++)
      #pragma unroll
      for (int kk = 0; kk < 2; kk++)
        a[fm][kk] = afrag(b, wr*128 + fm*16 + lr, kk);
    #pragma unroll
    for (int fn = 0; fn < 2; fn++)
      #pragma unroll
      for (int kk = 0; kk < 2; kk++)
        bb[fn][kk] = bfrag(b, wc*64 + fn*16 + lr, kk);
    if (t + 1 < NT) stage(t + 1, 3);
    __builtin_amdgcn_s_barrier();
    asm volatile("s_waitcnt lgkmcnt(0)" ::: "memory");
    __builtin_amdgcn_s_setprio(1);
    MFMA_QUAD(0, 0);
    __builtin_amdgcn_s_setprio(0);
    __builtin_amdgcn_s_barrier();
    // ---- phase 2: read B fn2,3 (4); stage (t+2,h0); MFMA quad m0n1
    #pragma unroll
    for (int fn = 2; fn < 4; fn++)
      #pragma unroll
      for (int kk = 0; kk < 2; kk++)
        bb[fn][kk] = bfrag(b, wc*64 + fn*16 + lr, kk);
    if (t + 2 < NT) stage(t + 2, 0);
    __builtin_amdgcn_s_barrier();
    asm volatile("s_waitcnt lgkmcnt(0)" ::: "memory");
    __builtin_amdgcn_s_setprio(1);
    MFMA_QUAD(0, 2);
    __builtin_amdgcn_s_setprio(0);
    __builtin_amdgcn_s_barrier();
    // ---- phase 3: stage (t+2,h1); MFMA quad m1n1
    if (t + 2 < NT) stage(t + 2, 1);
    __builtin_amdgcn_s_barrier();
    __builtin_amdgcn_s_setprio(1);
    MFMA_QUAD(4, 2);
    __builtin_amdgcn_s_setprio(0);
    __builtin_amdgcn_s_barrier();
    // ---- phase 4: stage (t+2,h2); MFMA quad m1n0; counted vmcnt; publish
    if (t + 2 < NT) stage(t + 2, 2);
    __builtin_amdgcn_s_barrier();
    __builtin_amdgcn_s_setprio(1);
    MFMA_QUAD(4, 0);
    __builtin_amdgcn_s_setprio(0);
    if (t < NT - 2) asm volatile("s_waitcnt vmcnt(6)" ::: "memory");
    else            asm volatile("s_waitcnt vmcnt(0)" ::: "memory");
    __builtin_amdgcn_s_barrier();
  }

  #pragma unroll
  for (int fm = 0; fm < 8; fm++) {
    #pragma unroll
    for (int fn = 0; fn < 4; fn++) {
      #pragma unroll
      for (int r2 = 0; r2 < 4; r2++) {
        int row = bm*256 + wr*128 + fm*16 + lg*4 + r2;
        int col = bn*256 + wc*64 + fn*16 + lr;
        if (WRITE_BF16) Cb[(size_t)row * N + col] = (bf16_t)acc[fm][fn][r2];
        else            Cf[(size_t)row * N + col] = acc[fm][fn][r2];
      }
    }
  }
}

// ---------------- fused RMSNorm (q over 4096, k over 1024) + RoPE + q-scale ----------------
__global__ __launch_bounds__(256) void normrope_kernel(bf16_t* __restrict__ qkv,
    const float* __restrict__ qw, const float* __restrict__ kw,
    const float* __restrict__ sc) {
  int t = blockIdx.x;
  int tid = threadIdx.x;
  bf16_t* qrow = qkv + (size_t)t * QKVD;
  bf16_t* krow = qrow + QD;
  __shared__ float red[8];
  float s = 0.f;
  {
    const bf16x8* p = (const bf16x8*)(qrow + tid*16);
    bf16x8 v0 = p[0], v1 = p[1];
    #pragma unroll
    for (int j = 0; j < 8; j++) { float a = (float)v0[j], b = (float)v1[j]; s += a*a + b*b; }
  }
  #pragma unroll
  for (int o = 32; o; o >>= 1) s += __shfl_xor(s, o);
  if ((tid & 63) == 0) red[tid >> 6] = s;
  float sk = 0.f;
  {
    bf16x4 v = *(const bf16x4*)(krow + tid*4);
    #pragma unroll
    for (int j = 0; j < 4; j++) { float a = (float)v[j]; sk += a*a; }
  }
  #pragma unroll
  for (int o = 32; o; o >>= 1) sk += __shfl_xor(sk, o);
  if ((tid & 63) == 0) red[4 + (tid >> 6)] = sk;
  __syncthreads();
  float rq = rsqrtf((red[0]+red[1]+red[2]+red[3]) / (float)QD + 1e-6f);
  float rk = rsqrtf((red[4]+red[5]+red[6]+red[7]) / (float)KD + 1e-6f);
  const float ascale = 0.08838834764831845f; // 1/sqrt(128), folded into Q
  for (int p = tid; p < 2048; p += 256) {   // 32 heads * 64 pairs
    int hh = p >> 6, i = p & 63;
    int i1 = hh*HD + i, i2 = i1 + 64;
    float x1 = (float)qrow[i1] * rq * qw[i1];
    float x2 = (float)qrow[i2] * rq * qw[i2];
    float sn = sc[(t*64 + i)*2 + 0], cs = sc[(t*64 + i)*2 + 1];
    qrow[i1] = (bf16_t)((x1*cs - x2*sn) * ascale);
    qrow[i2] = (bf16_t)((x2*cs + x1*sn) * ascale);
  }
  for (int p = tid; p < 512; p += 256) {    // 8 kv heads * 64 pairs
    int hh = p >> 6, i = p & 63;
    int i1 = hh*HD + i, i2 = i1 + 64;
    float x1 = (float)krow[i1] * rk * kw[i1];
    float x2 = (float)krow[i2] * rk * kw[i2];
    float sn = sc[(t*64 + i)*2 + 0], cs = sc[(t*64 + i)*2 + 1];
    krow[i1] = (bf16_t)(x1*cs - x2*sn);
    krow[i2] = (bf16_t)(x2*cs + x1*sn);
  }
}

// ---------------- flash attention, sliding window, GQA ----------------
__global__ __launch_bounds__(256) void attn_kernel(const bf16_t* __restrict__ qkv,
    const int* __restrict__ positions, const int* __restrict__ seg,
    bf16_t* __restrict__ O) {
  __shared__ bf16_t Vt[HD * VS];      // V tile transposed: [128 d][64 keys + pad]
  __shared__ bf16_t P[4][16 * VS];    // per-wave P tile [16 q][64 keys + pad]
  int tid = threadIdx.x;
  int w = tid >> 6, l = tid & 63, lr = l & 15, lg = l >> 4;
  int qb = blockIdx.x * 64;
  int h = blockIdx.y;
  int kvh = h >> 2;
  int q0 = qb + w * 16;
  bf16x8 qf[4];
  {
    const bf16_t* Qrow = qkv + (size_t)(q0 + lr) * QKVD + h * HD;
    #pragma unroll
    for (int c = 0; c < 4; c++) qf[c] = *(const bf16x8*)(Qrow + c*32 + lg*8);
  }
  int pos_i[4], seg_i[4];
  #pragma unroll
  for (int r = 0; r < 4; r++) { int i = q0 + lg*4 + r; pos_i[r] = positions[i]; seg_i[r] = seg[i]; }
  f32x4 o[8] = {};
  float m[4], lsum[4];
  #pragma unroll
  for (int r = 0; r < 4; r++) { m[r] = -__builtin_inff(); lsum[r] = 0.f; }
  int jstart = qb - (WIN - 1); if (jstart < 0) jstart = 0; jstart &= ~63;
  for (int j0 = jstart; j0 <= qb; j0 += 64) {
    #pragma unroll
    for (int si = 0; si < 2; si++) {
      int item = tid + si * 256;
      int kp = item & 31, dg = item >> 5;
      const bf16_t* v0p = qkv + (size_t)(j0 + 2*kp) * QKVD + QD + KD + kvh*HD + dg*8;
      bf16x8 vA = *(const bf16x8*)(v0p);
      bf16x8 vB = *(const bf16x8*)(v0p + QKVD);
      #pragma unroll
      for (int e = 0; e < 8; e++) {
        bf16x2 pr; pr[0] = vA[e]; pr[1] = vB[e];
        *(bf16x2*)(Vt + (dg*8 + e)*VS + 2*kp) = pr;
      }
    }
    __syncthreads();
    bool active = (j0 <= q0 + 15) && (j0 + 63 >= q0 - (WIN - 1));
    if (active) {
      f32x4 s[4] = {};
      #pragma unroll
      for (int kt = 0; kt < 4; kt++) {
        const bf16_t* Krow = qkv + (size_t)(j0 + kt*16 + lr) * QKVD + QD + kvh*HD;
        #pragma unroll
        for (int c = 0; c < 4; c++) {
          bf16x8 kf = *(const bf16x8*)(Krow + c*32 + lg*8);
          s[kt] = __builtin_amdgcn_mfma_f32_16x16x32_bf16(qf[c], kf, s[kt], 0, 0, 0);
        }
      }
      #pragma unroll
      for (int kt = 0; kt < 4; kt++) {
        int j = j0 + kt*16 + lr;
        int pj = positions[j]; int sj = seg[j];
        #pragma unroll
        for (int r = 0; r < 4; r++) {
          bool valid = (pj <= pos_i[r]) && (pos_i[r] - pj < WIN) && (seg_i[r] == sj) && (sj != 0);
          s[kt][r] = valid ? s[kt][r] : -__builtin_inff();
        }
      }
      #pragma unroll
      for (int r = 0; r < 4; r++) {
        float rm = fmaxf(fmaxf(s[0][r], s[1][r]), fmaxf(s[2][r], s[3][r]));
        #pragma unroll
        for (int o2 = 1; o2 < 16; o2 <<= 1) rm = fmaxf(rm, __shfl_xor(rm, o2));
        if (rm > m[r] + 8.f) {
          float rescale = __expf(m[r] - rm);
          lsum[r] *= rescale;
          #pragma unroll
          for (int n = 0; n < 8; n++) o[n][r] *= rescale;
          m[r] = rm;
        }
        float mub = fmaxf(m[r], -1e37f);
        float p0 = __expf(s[0][r] - mub);
        float p1 = __expf(s[1][r] - mub);
        float p2 = __expf(s[2][r] - mub);
        float p3 = __expf(s[3][r] - mub);
        float rs = (p0 + p1) + (p2 + p3);
        #pragma unroll
        for (int o2 = 1; o2 < 16; o2 <<= 1) rs += __shfl_xor(rs, o2);
        lsum[r] += rs;
        int prow = (lg*4 + r) * VS;
        P[w][prow + lr]      = (bf16_t)p0;
        P[w][prow + 16 + lr] = (bf16_t)p1;
        P[w][prow + 32 + lr] = (bf16_t)p2;
        P[w][prow + 48 + lr] = (bf16_t)p3;
      }
    }
    __syncthreads();
    if (active) {
      #pragma unroll
      for (int ks = 0; ks < 2; ks++) {
        bf16x8 pa = *(const bf16x8*)(&P[w][lr*VS + ks*32 + lg*8]);
        #pragma unroll
        for (int n = 0; n < 8; n++) {
          bf16x8 vb = *(const bf16x8*)(&Vt[(n*16 + lr)*VS + ks*32 + lg*8]);
          o[n] = __builtin_amdgcn_mfma_f32_16x16x32_bf16(pa, vb, o[n], 0, 0, 0);
        }
      }
    }
    __syncthreads();
  }
  #pragma unroll
  for (int r = 0; r < 4; r++) {
    float inv = lsum[r] > 0.f ? 1.f / lsum[r] : 0.f;
    int row = q0 + lg*4 + r;
    #pragma unroll
    for (int n = 0; n < 8; n++)
      O[(size_t)row * QD + h*HD + n*16 + lr] = (bf16_t)(o[n][r] * inv);
  }
}

// ---------------- launch ----------------
extern "C" void kernel_launch(void* const* d_in, const int* in_sizes, int n_in,
                              void* d_out, int out_size, void* d_ws, size_t ws_size,
                              hipStream_t stream) {
  (void)in_sizes; (void)n_in; (void)out_size; (void)ws_size;
  const float* x  = (const float*)d_in[0];
  const float* Wq = (const float*)d_in[1];
  const float* Wk = (const float*)d_in[2];
  const float* Wv = (const float*)d_in[3];
  const float* Wo = (const float*)d_in[4];
  const float* qw = (const float*)d_in[5];
  const float* kw = (const float*)d_in[6];
  const int*  seg = (const int*)d_in[7];
  float* out = (float*)d_out;

  char* base = (char*)d_ws;
  size_t off = 0;
  auto alloc = [&](size_t b) { void* r = base + off; off = (off + b + 255) & ~(size_t)255; return r; };
  bf16_t* xb    = (bf16_t*)alloc((size_t)T_LEN * DMODEL * 2);
  bf16_t* Wallt = (bf16_t*)alloc((size_t)QKVD * DMODEL * 2);
  bf16_t* Wot   = (bf16_t*)alloc((size_t)DMODEL * QD * 2);
  bf16_t* qkv   = (bf16_t*)alloc((size_t)T_LEN * QKVD * 2);
  int*    posi  = (int*)alloc((size_t)T_LEN * 4);
  float*  sc    = (float*)alloc((size_t)T_LEN * 64 * 2 * 4);
  bf16_t* ao    = xb;  // attention output aliases xb (xb dead after GEMM1)

  pos_kernel<<<1, 256, 0, stream>>>(seg, posi);
  sincos_kernel<<<T_LEN, 64, 0, stream>>>(posi, sc);
  cvt_kernel<<<(T_LEN * DMODEL / 8 + 255) / 256, 256, 0, stream>>>(x, xb, T_LEN * DMODEL);
  transcvt_kernel<<<dim3(QD/32, DMODEL/32), dim3(32, 8), 0, stream>>>(Wq, Wallt, DMODEL, QD);
  transcvt_kernel<<<dim3(KD/32, DMODEL/32), dim3(32, 8), 0, stream>>>(Wk, Wallt + (size_t)QD * DMODEL, DMODEL, KD);
  transcvt_kernel<<<dim3(KD/32, DMODEL/32), dim3(32, 8), 0, stream>>>(Wv, Wallt + (size_t)(QD + KD) * DMODEL, DMODEL, KD);
  transcvt_kernel<<<dim3(DMODEL/32, QD/32), dim3(32, 8), 0, stream>>>(Wo, Wot, QD, DMODEL);
  gemm256_kernel<true><<<dim3((T_LEN/256)*(QKVD/256)), 512, 0, stream>>>(xb, Wallt, qkv, nullptr, T_LEN, QKVD, DMODEL, QKVD/256);
  normrope_kernel<<<T_LEN, 256, 0, stream>>>(qkv, qw, kw, sc);
  attn_kernel<<<dim3(T_LEN/64, NHEADS), 256, 0, stream>>>(qkv, posi, seg, ao);
  gemm256_kernel<false><<<dim3((T_LEN/256)*(DMODEL/256)), 512, 0, stream>>>(ao, Wot, nullptr, out, T_LEN, DMODEL, QD, DMODEL/256);
}

// Round 4
// 434.820 us; speedup vs baseline: 1.4832x; 1.1419x over previous
//
#include <hip/hip_runtime.h>
#include <cstdint>
#include <cstddef>

typedef __bf16 bf16_t;
typedef __bf16 bf16x8 __attribute__((ext_vector_type(8)));
typedef __bf16 bf16x4 __attribute__((ext_vector_type(4)));
typedef __bf16 bf16x2 __attribute__((ext_vector_type(2)));
typedef float f32x4 __attribute__((ext_vector_type(4)));

#define T_LEN 2048
#define DMODEL 4096
#define NHEADS 32
#define KVHEADS 8
#define HD 128
#define QD 4096   // NHEADS*HD
#define KD 1024   // KVHEADS*HD
#define QKVD 6144 // QD + 2*KD
#define WIN 1024
#define VS 72     // padded stride for attn Vt/P tiles

// ---------------- positions (argmax of segment row, first occurrence) ----------------
__global__ void pos_kernel(const int* __restrict__ seg, int* __restrict__ positions) {
  __shared__ int svals[256], sidx[256];
  int tid = threadIdx.x;
  int bestv = -2147483647 - 1, besti = 0;
  for (int t = tid; t < T_LEN; t += 256) {
    int v = seg[t];
    if (v > bestv) { bestv = v; besti = t; }
  }
  svals[tid] = bestv; sidx[tid] = besti;
  __syncthreads();
  for (int st = 128; st > 0; st >>= 1) {
    if (tid < st) {
      if (svals[tid+st] > svals[tid] || (svals[tid+st] == svals[tid] && sidx[tid+st] < sidx[tid])) {
        svals[tid] = svals[tid+st]; sidx[tid] = sidx[tid+st];
      }
    }
    __syncthreads();
  }
  int amax = sidx[0];
  for (int t = tid; t < T_LEN; t += 256)
    positions[t] = (seg[t] != 0) ? (t - amax) : (1 << 30);
}

// ---------------- rope sin/cos table: sc[t][i][2], i in [0,64) ----------------
__global__ void sincos_kernel(const int* __restrict__ positions, float* __restrict__ sc) {
  int t = blockIdx.x, i = threadIdx.x; // 64 threads
  float inv = expf(-(float)i * (logf(500000.0f) / 64.0f));
  float ang = (float)positions[t] * inv;
  sc[(t*64 + i)*2 + 0] = sinf(ang);
  sc[(t*64 + i)*2 + 1] = cosf(ang);
}

// ---------------- f32 -> bf16 convert (8/thread) ----------------
__global__ void cvt_kernel(const float* __restrict__ in, bf16_t* __restrict__ out, int n) {
  int i = (blockIdx.x * blockDim.x + threadIdx.x) * 8;
  if (i >= n) return;
  float4 a = *(const float4*)(in + i);
  float4 b = *(const float4*)(in + i + 4);
  bf16x8 o;
  o[0]=(bf16_t)a.x; o[1]=(bf16_t)a.y; o[2]=(bf16_t)a.z; o[3]=(bf16_t)a.w;
  o[4]=(bf16_t)b.x; o[5]=(bf16_t)b.y; o[6]=(bf16_t)b.z; o[7]=(bf16_t)b.w;
  *(bf16x8*)(out + i) = o;
}

// ---------------- transpose + convert: W[K][N] f32 -> Wt[N][K] bf16 ----------------
__global__ void transcvt_kernel(const float* __restrict__ W, bf16_t* __restrict__ Wt, int K, int N) {
  __shared__ float tile[32][33];
  int tx = threadIdx.x, ty = threadIdx.y; // 32 x 8
  int bx = blockIdx.x, by = blockIdx.y;
  #pragma unroll
  for (int i = 0; i < 4; i++) {
    int k = by*32 + ty + i*8;
    tile[ty + i*8][tx] = W[(size_t)k * N + bx*32 + tx];
  }
  __syncthreads();
  #pragma unroll
  for (int i = 0; i < 4; i++) {
    int n = bx*32 + ty + i*8;
    Wt[(size_t)n * K + by*32 + tx] = (bf16_t)tile[tx][ty + i*8];
  }
}

// ---------------- 256x256 8-phase bf16 GEMM (T1+T2+T3+T4+T5) ----------------
__device__ __forceinline__ void gld_lds16(const void* g, void* l) {
  __builtin_amdgcn_global_load_lds((__attribute__((address_space(1))) void*)g,
                                   (__attribute__((address_space(3))) void*)l, 16, 0, 0);
}

#define MFMA_QUAD(FM0, FN0)                                                     \
  { _Pragma("unroll") for (int fm_ = 0; fm_ < 4; fm_++)                          \
    _Pragma("unroll") for (int fn_ = 0; fn_ < 2; fn_++)                          \
    _Pragma("unroll") for (int kk_ = 0; kk_ < 2; kk_++)                          \
      acc[(FM0)+fm_][(FN0)+fn_] = __builtin_amdgcn_mfma_f32_16x16x32_bf16(       \
          a[(FM0)+fm_][kk_], bb[(FN0)+fn_][kk_], acc[(FM0)+fm_][(FN0)+fn_], 0,0,0); }

template<bool WRITE_BF16>
__global__ __launch_bounds__(512, 2) void gemm256_kernel(
    const bf16_t* __restrict__ A, const bf16_t* __restrict__ Bt,
    bf16_t* __restrict__ Cb, float* __restrict__ Cf,
    int M, int N, int K, int NBN) {
  __shared__ bf16_t As[2 * 256 * 64];
  __shared__ bf16_t Bs[2 * 256 * 64];
  int tid = threadIdx.x;
  int w = tid >> 6, l = tid & 63, lr = l & 15, lg = l >> 4;
  int wr = w >> 2, wc = w & 3;
  int nwg = gridDim.x;
  int wg  = blockIdx.x;
  int cpx = nwg >> 3;
  int swz = (wg & 7) * cpx + (wg >> 3);
  int bm = swz / NBN, bn = swz % NBN;
  const int NT = K >> 6;

  auto stage = [&](int tt, int h) {
    int b2 = tt & 1;
    const bf16_t* G; size_t grow0; bf16_t* ldsb;
    if (h < 2) { G = A;  grow0 = (size_t)bm*256 + h*128;       ldsb = As + b2*16384 + h*8192; }
    else       { G = Bt; grow0 = (size_t)bn*256 + (h-2)*128;   ldsb = Bs + b2*16384 + (h-2)*8192; }
    int kcol = tt * 64;
    #pragma unroll
    for (int r2 = 0; r2 < 2; r2++) {
      int L = r2*8192 + tid*16;
      int row = L >> 7;
      int chunk = (L >> 4) & 7;
      int scn = chunk ^ (row & 7);
      gld_lds16(G + (grow0 + (size_t)row) * K + kcol + scn*8,
                ldsb + r2*4096 + w*512);
    }
  };
  auto afrag = [&](int b2, int row, int kk) -> bf16x8 {
    int chunk = (kk*4 + lg) ^ (row & 7);
    return *(const bf16x8*)((const char*)(As + b2*16384) + row*128 + chunk*16);
  };
  auto bfrag = [&](int b2, int row, int kk) -> bf16x8 {
    int chunk = (kk*4 + lg) ^ (row & 7);
    return *(const bf16x8*)((const char*)(Bs + b2*16384) + row*128 + chunk*16);
  };

  f32x4 acc[8][4] = {};
  bf16x8 a[8][2], bb[4][2];

  #pragma unroll
  for (int h = 0; h < 4; h++) stage(0, h);
  #pragma unroll
  for (int h = 0; h < 3; h++) stage(1, h);
  asm volatile("s_waitcnt vmcnt(6)" ::: "memory");
  __builtin_amdgcn_s_barrier();

  for (int t = 0; t < NT; t++) {
    int b = t & 1;
    #pragma unroll
    for (int fm = 0; fm < 8; fm++)
      #pragma unroll
      for (int kk = 0; kk < 2; kk++)
        a[fm][kk] = afrag(b, wr*128 + fm*16 + lr, kk);
    #pragma unroll
    for (int fn = 0; fn < 2; fn++)
      #pragma unroll
      for (int kk = 0; kk < 2; kk++)
        bb[fn][kk] = bfrag(b, wc*64 + fn*16 + lr, kk);
    if (t + 1 < NT) stage(t + 1, 3);
    __builtin_amdgcn_s_barrier();
    asm volatile("s_waitcnt lgkmcnt(0)" ::: "memory");
    __builtin_amdgcn_s_setprio(1);
    MFMA_QUAD(0, 0);
    __builtin_amdgcn_s_setprio(0);
    __builtin_amdgcn_s_barrier();
    #pragma unroll
    for (int fn = 2; fn < 4; fn++)
      #pragma unroll
      for (int kk = 0; kk < 2; kk++)
        bb[fn][kk] = bfrag(b, wc*64 + fn*16 + lr, kk);
    if (t + 2 < NT) stage(t + 2, 0);
    __builtin_amdgcn_s_barrier();
    asm volatile("s_waitcnt lgkmcnt(0)" ::: "memory");
    __builtin_amdgcn_s_setprio(1);
    MFMA_QUAD(0, 2);
    __builtin_amdgcn_s_setprio(0);
    __builtin_amdgcn_s_barrier();
    if (t + 2 < NT) stage(t + 2, 1);
    __builtin_amdgcn_s_barrier();
    __builtin_amdgcn_s_setprio(1);
    MFMA_QUAD(4, 2);
    __builtin_amdgcn_s_setprio(0);
    __builtin_amdgcn_s_barrier();
    if (t + 2 < NT) stage(t + 2, 2);
    __builtin_amdgcn_s_barrier();
    __builtin_amdgcn_s_setprio(1);
    MFMA_QUAD(4, 0);
    __builtin_amdgcn_s_setprio(0);
    if (t < NT - 2) asm volatile("s_waitcnt vmcnt(6)" ::: "memory");
    else            asm volatile("s_waitcnt vmcnt(0)" ::: "memory");
    __builtin_amdgcn_s_barrier();
  }

  #pragma unroll
  for (int fm = 0; fm < 8; fm++) {
    #pragma unroll
    for (int fn = 0; fn < 4; fn++) {
      #pragma unroll
      for (int r2 = 0; r2 < 4; r2++) {
        int row = bm*256 + wr*128 + fm*16 + lg*4 + r2;
        int col = bn*256 + wc*64 + fn*16 + lr;
        if (WRITE_BF16) Cb[(size_t)row * N + col] = (bf16_t)acc[fm][fn][r2];
        else            Cf[(size_t)row * N + col] = acc[fm][fn][r2];
      }
    }
  }
}

// ---------------- fused RMSNorm (q over 4096, k over 1024) + RoPE + q-scale ----------------
__global__ __launch_bounds__(256) void normrope_kernel(bf16_t* __restrict__ qkv,
    const float* __restrict__ qw, const float* __restrict__ kw,
    const float* __restrict__ sc) {
  int t = blockIdx.x;
  int tid = threadIdx.x;
  bf16_t* qrow = qkv + (size_t)t * QKVD;
  bf16_t* krow = qrow + QD;
  __shared__ float red[8];
  float s = 0.f;
  {
    const bf16x8* p = (const bf16x8*)(qrow + tid*16);
    bf16x8 v0 = p[0], v1 = p[1];
    #pragma unroll
    for (int j = 0; j < 8; j++) { float a = (float)v0[j], b = (float)v1[j]; s += a*a + b*b; }
  }
  #pragma unroll
  for (int o = 32; o; o >>= 1) s += __shfl_xor(s, o);
  if ((tid & 63) == 0) red[tid >> 6] = s;
  float sk = 0.f;
  {
    bf16x4 v = *(const bf16x4*)(krow + tid*4);
    #pragma unroll
    for (int j = 0; j < 4; j++) { float a = (float)v[j]; sk += a*a; }
  }
  #pragma unroll
  for (int o = 32; o; o >>= 1) sk += __shfl_xor(sk, o);
  if ((tid & 63) == 0) red[4 + (tid >> 6)] = sk;
  __syncthreads();
  float rq = rsqrtf((red[0]+red[1]+red[2]+red[3]) / (float)QD + 1e-6f);
  float rk = rsqrtf((red[4]+red[5]+red[6]+red[7]) / (float)KD + 1e-6f);
  const float ascale = 0.08838834764831845f; // 1/sqrt(128), folded into Q
  for (int p = tid; p < 2048; p += 256) {
    int hh = p >> 6, i = p & 63;
    int i1 = hh*HD + i, i2 = i1 + 64;
    float x1 = (float)qrow[i1] * rq * qw[i1];
    float x2 = (float)qrow[i2] * rq * qw[i2];
    float sn = sc[(t*64 + i)*2 + 0], cs = sc[(t*64 + i)*2 + 1];
    qrow[i1] = (bf16_t)((x1*cs - x2*sn) * ascale);
    qrow[i2] = (bf16_t)((x2*cs + x1*sn) * ascale);
  }
  for (int p = tid; p < 512; p += 256) {
    int hh = p >> 6, i = p & 63;
    int i1 = hh*HD + i, i2 = i1 + 64;
    float x1 = (float)krow[i1] * rk * kw[i1];
    float x2 = (float)krow[i2] * rk * kw[i2];
    float sn = sc[(t*64 + i)*2 + 0], cs = sc[(t*64 + i)*2 + 1];
    krow[i1] = (bf16_t)(x1*cs - x2*sn);
    krow[i2] = (bf16_t)(x2*cs + x1*sn);
  }
}

// ---------------- flash attention, sliding window, GQA ----------------
// grid: (T/64, NHEADS); 4 waves x 16 q rows. KV tile = 64 keys.
// K reg-staged into swizzled LDS with one-tile prefetch; raw barriers keep
// K(t+1) global loads in flight across the tile's compute.
__global__ __launch_bounds__(256, 3) void attn_kernel(const bf16_t* __restrict__ qkv,
    const int* __restrict__ positions, const int* __restrict__ seg,
    bf16_t* __restrict__ O) {
  __shared__ bf16_t Ks[64 * HD];      // 16 KB, 16B-chunk XOR swizzle
  __shared__ bf16_t Vt[HD * VS];      // V tile transposed [128 d][64 keys + pad]
  __shared__ bf16_t P[4][16 * VS];    // per-wave P tile
  int tid = threadIdx.x;
  int w = tid >> 6, l = tid & 63, lr = l & 15, lg = l >> 4;
  int qb = blockIdx.x * 64;
  int h = blockIdx.y;
  int kvh = h >> 2;
  int q0 = qb + w * 16;
  const bf16_t* Kg = qkv + QD + (size_t)kvh * HD;
  const bf16_t* Vg = qkv + QD + KD + (size_t)kvh * HD;

  bf16x8 qf[4];
  {
    const bf16_t* Qrow = qkv + (size_t)(q0 + lr) * QKVD + h * HD;
    #pragma unroll
    for (int c = 0; c < 4; c++) qf[c] = *(const bf16x8*)(Qrow + c*32 + lg*8);
  }
  int pos_i[4], seg_i[4];
  #pragma unroll
  for (int r = 0; r < 4; r++) { int i = q0 + lg*4 + r; pos_i[r] = positions[i]; seg_i[r] = seg[i]; }
  f32x4 o[8] = {};
  float m[4], lsum[4];
  #pragma unroll
  for (int r = 0; r < 4; r++) { m[r] = -__builtin_inff(); lsum[r] = 0.f; }

  // per-thread K chunk ids: c = tid + i*256; row = c>>4 (16 chunks of 16B per row)
  int krow_[4], kscn_[4];
  #pragma unroll
  for (int i = 0; i < 4; i++) {
    int c = tid + i*256;
    krow_[i] = c >> 4;
    kscn_[i] = (c & 15) ^ (krow_[i] & 7);
  }
  bf16x8 kreg[4];

  int jstart = qb - (WIN - 1); if (jstart < 0) jstart = 0; jstart &= ~63;
  // prologue: load K(jstart) into regs
  #pragma unroll
  for (int i = 0; i < 4; i++)
    kreg[i] = *(const bf16x8*)(Kg + (size_t)(jstart + krow_[i]) * QKVD + kscn_[i]*8);

  for (int j0 = jstart; j0 <= qb; j0 += 64) {
    // ---- Phase A: commit K(t) regs to LDS, stage V(t), prefetch K(t+1)+mask ----
    #pragma unroll
    for (int i = 0; i < 4; i++)
      *(bf16x8*)((char*)Ks + (tid + i*256)*16) = kreg[i];
    #pragma unroll
    for (int si = 0; si < 2; si++) {
      int item = tid + si * 256;
      int kp = item & 31, dg = item >> 5;
      const bf16_t* v0p = Vg + (size_t)(j0 + 2*kp) * QKVD + dg*8;
      bf16x8 vA = *(const bf16x8*)(v0p);
      bf16x8 vB = *(const bf16x8*)(v0p + QKVD);
      #pragma unroll
      for (int e = 0; e < 8; e++) {
        bf16x2 pr; pr[0] = vA[e]; pr[1] = vB[e];
        *(bf16x2*)(Vt + (dg*8 + e)*VS + 2*kp) = pr;
      }
    }
    int pj[4], sj[4];
    #pragma unroll
    for (int kt = 0; kt < 4; kt++) { int j = j0 + kt*16 + lr; pj[kt] = positions[j]; sj[kt] = seg[j]; }
    if (j0 + 64 <= qb) {
      #pragma unroll
      for (int i = 0; i < 4; i++)
        kreg[i] = *(const bf16x8*)(Kg + (size_t)(j0 + 64 + krow_[i]) * QKVD + kscn_[i]*8);
    }
    asm volatile("" :: "v"(pj[0]), "v"(pj[1]), "v"(pj[2]), "v"(pj[3]),
                       "v"(sj[0]), "v"(sj[1]), "v"(sj[2]), "v"(sj[3]));
    asm volatile("s_waitcnt lgkmcnt(0)" ::: "memory");
    __builtin_amdgcn_s_barrier();

    // ---- Phase B: QK^T from swizzled LDS + softmax; Phase C: PV ----
    bool active = (j0 <= q0 + 15) && (j0 + 63 >= q0 - (WIN - 1));
    if (active) {
      f32x4 s[4] = {};
      #pragma unroll
      for (int kt = 0; kt < 4; kt++) {
        int row = kt*16 + lr;
        const char* kb = (const char*)Ks + row*256;
        #pragma unroll
        for (int c = 0; c < 4; c++) {
          bf16x8 kf = *(const bf16x8*)(kb + (((c*4 + lg) ^ (row & 7)) * 16));
          s[kt] = __builtin_amdgcn_mfma_f32_16x16x32_bf16(qf[c], kf, s[kt], 0, 0, 0);
        }
      }
      #pragma unroll
      for (int kt = 0; kt < 4; kt++) {
        #pragma unroll
        for (int r = 0; r < 4; r++) {
          bool valid = (pj[kt] <= pos_i[r]) && (pos_i[r] - pj[kt] < WIN) && (seg_i[r] == sj[kt]) && (sj[kt] != 0);
          s[kt][r] = valid ? s[kt][r] : -__builtin_inff();
        }
      }
      #pragma unroll
      for (int r = 0; r < 4; r++) {
        float rm = fmaxf(fmaxf(s[0][r], s[1][r]), fmaxf(s[2][r], s[3][r]));
        #pragma unroll
        for (int o2 = 1; o2 < 16; o2 <<= 1) rm = fmaxf(rm, __shfl_xor(rm, o2));
        if (rm > m[r] + 8.f) {
          float rescale = __expf(m[r] - rm);
          lsum[r] *= rescale;
          #pragma unroll
          for (int n = 0; n < 8; n++) o[n][r] *= rescale;
          m[r] = rm;
        }
        float mub = fmaxf(m[r], -1e37f);
        float p0 = __expf(s[0][r] - mub);
        float p1 = __expf(s[1][r] - mub);
        float p2 = __expf(s[2][r] - mub);
        float p3 = __expf(s[3][r] - mub);
        float rs = (p0 + p1) + (p2 + p3);
        #pragma unroll
        for (int o2 = 1; o2 < 16; o2 <<= 1) rs += __shfl_xor(rs, o2);
        lsum[r] += rs;
        int prow = (lg*4 + r) * VS;
        P[w][prow + lr]      = (bf16_t)p0;
        P[w][prow + 16 + lr] = (bf16_t)p1;
        P[w][prow + 32 + lr] = (bf16_t)p2;
        P[w][prow + 48 + lr] = (bf16_t)p3;
      }
      #pragma unroll
      for (int ks = 0; ks < 2; ks++) {
        bf16x8 pa = *(const bf16x8*)(&P[w][lr*VS + ks*32 + lg*8]);
        #pragma unroll
        for (int n = 0; n < 8; n++) {
          bf16x8 vb = *(const bf16x8*)(&Vt[(n*16 + lr)*VS + ks*32 + lg*8]);
          o[n] = __builtin_amdgcn_mfma_f32_16x16x32_bf16(pa, vb, o[n], 0, 0, 0);
        }
      }
    }
    asm volatile("s_waitcnt lgkmcnt(0)" ::: "memory");
    __builtin_amdgcn_s_barrier();
  }
  #pragma unroll
  for (int r = 0; r < 4; r++) {
    float inv = lsum[r] > 0.f ? 1.f / lsum[r] : 0.f;
    int row = q0 + lg*4 + r;
    #pragma unroll
    for (int n = 0; n < 8; n++)
      O[(size_t)row * QD + h*HD + n*16 + lr] = (bf16_t)(o[n][r] * inv);
  }
}

// ---------------- launch ----------------
extern "C" void kernel_launch(void* const* d_in, const int* in_sizes, int n_in,
                              void* d_out, int out_size, void* d_ws, size_t ws_size,
                              hipStream_t stream) {
  (void)in_sizes; (void)n_in; (void)out_size; (void)ws_size;
  const float* x  = (const float*)d_in[0];
  const float* Wq = (const float*)d_in[1];
  const float* Wk = (const float*)d_in[2];
  const float* Wv = (const float*)d_in[3];
  const float* Wo = (const float*)d_in[4];
  const float* qw = (const float*)d_in[5];
  const float* kw = (const float*)d_in[6];
  const int*  seg = (const int*)d_in[7];
  float* out = (float*)d_out;

  char* base = (char*)d_ws;
  size_t off = 0;
  auto alloc = [&](size_t b) { void* r = base + off; off = (off + b + 255) & ~(size_t)255; return r; };
  bf16_t* xb    = (bf16_t*)alloc((size_t)T_LEN * DMODEL * 2);
  bf16_t* Wallt = (bf16_t*)alloc((size_t)QKVD * DMODEL * 2);
  bf16_t* Wot   = (bf16_t*)alloc((size_t)DMODEL * QD * 2);
  bf16_t* qkv   = (bf16_t*)alloc((size_t)T_LEN * QKVD * 2);
  int*    posi  = (int*)alloc((size_t)T_LEN * 4);
  float*  sc    = (float*)alloc((size_t)T_LEN * 64 * 2 * 4);
  bf16_t* ao    = xb;  // attention output aliases xb (xb dead after GEMM1)

  pos_kernel<<<1, 256, 0, stream>>>(seg, posi);
  sincos_kernel<<<T_LEN, 64, 0, stream>>>(posi, sc);
  cvt_kernel<<<(T_LEN * DMODEL / 8 + 255) / 256, 256, 0, stream>>>(x, xb, T_LEN * DMODEL);
  transcvt_kernel<<<dim3(QD/32, DMODEL/32), dim3(32, 8), 0, stream>>>(Wq, Wallt, DMODEL, QD);
  transcvt_kernel<<<dim3(KD/32, DMODEL/32), dim3(32, 8), 0, stream>>>(Wk, Wallt + (size_t)QD * DMODEL, DMODEL, KD);
  transcvt_kernel<<<dim3(KD/32, DMODEL/32), dim3(32, 8), 0, stream>>>(Wv, Wallt + (size_t)(QD + KD) * DMODEL, DMODEL, KD);
  transcvt_kernel<<<dim3(DMODEL/32, QD/32), dim3(32, 8), 0, stream>>>(Wo, Wot, QD, DMODEL);
  gemm256_kernel<true><<<dim3((T_LEN/256)*(QKVD/256)), 512, 0, stream>>>(xb, Wallt, qkv, nullptr, T_LEN, QKVD, DMODEL, QKVD/256);
  normrope_kernel<<<T_LEN, 256, 0, stream>>>(qkv, qw, kw, sc);
  attn_kernel<<<dim3(T_LEN/64, NHEADS), 256, 0, stream>>>(qkv, posi, seg, ao);
  gemm256_kernel<false><<<dim3((T_LEN/256)*(DMODEL/256)), 512, 0, stream>>>(ao, Wot, nullptr, out, T_LEN, DMODEL, QD, DMODEL/256);
}